// Round 1
// baseline (515.769 us; speedup 1.0000x reference)
//
#include <hip/hip_runtime.h>

// MAF_Extractor: projection -> bilinear grid_sample (B,C,H,W)@(B,N,2) -> 3-layer MLP
// B=64 N=431 C=256 H=W=56; dims 256->128, (128+256)->64, (64+256)->5
// Fused single kernel: one block = 16 points of one batch; 256 threads.

#define B_   64
#define N_   431
#define C_   256
#define H_   56
#define W_   56
#define HW_  (H_ * W_)
#define PPB  16            // points per block
#define NT_  27            // ceil(431/16)

__global__ __launch_bounds__(256, 4) void maf_fused_kernel(
    const float* __restrict__ p,     // (B,N,3)
    const float* __restrict__ cam,   // (B,3)
    const float* __restrict__ sfeat, // (B,C,H,W)
    const float* __restrict__ W0,    // (128,256)
    const float* __restrict__ b0,    // (128)
    const float* __restrict__ W1,    // (64,384)
    const float* __restrict__ b1,    // (64)
    const float* __restrict__ W2,    // (5,320)
    const float* __restrict__ b2,    // (5)
    float* __restrict__ out)         // (B, 5*N) as (B,5,N)
{
    __shared__ float feat_s[PPB][C_];   // 16 KB
    __shared__ float y0_s[PPB][128];    // 8 KB
    __shared__ float y1_s[PPB][64];     // 4 KB

    const int tid  = threadIdx.x;
    const int tile = blockIdx.x;        // 0..26
    const int b    = blockIdx.y;        // 0..63
    const int n0   = tile * PPB;

    const float s  = cam[b * 3 + 0];
    const float tx = cam[b * 3 + 1];
    const float ty = cam[b * 3 + 2];

    // ---------------- Phase 1: bilinear gather (thread = channel) ----------------
    {
        const int c = tid;  // 0..255
        const float* __restrict__ fb = sfeat + ((size_t)b * C_ + c) * HW_;
        #pragma unroll 4
        for (int pp = 0; pp < PPB; ++pp) {
            const int n = n0 + pp;
            float val = 0.f;
            if (n < N_) {
                const float px = p[((size_t)b * N_ + n) * 3 + 0];
                const float py = p[((size_t)b * N_ + n) * 3 + 1];
                // x = (s*(px+tx) + 1) * 0.5 * (W-1)
                const float x = (s * (px + tx) + 1.f) * 0.5f * (float)(W_ - 1);
                const float y = (s * (py + ty) + 1.f) * 0.5f * (float)(H_ - 1);
                const float x0f = floorf(x), y0f = floorf(y);
                const float wx1 = x - x0f, wx0 = 1.f - wx1;
                const float wy1 = y - y0f, wy0 = 1.f - wy1;
                const int ix0 = (int)x0f, iy0 = (int)y0f;
                const int ix1 = ix0 + 1,  iy1 = iy0 + 1;
                const bool vx0 = (ix0 >= 0) & (ix0 <= W_ - 1);
                const bool vx1 = (ix1 >= 0) & (ix1 <= W_ - 1);
                const bool vy0 = (iy0 >= 0) & (iy0 <= H_ - 1);
                const bool vy1 = (iy1 >= 0) & (iy1 <= H_ - 1);
                const int cx0 = min(max(ix0, 0), W_ - 1);
                const int cx1 = min(max(ix1, 0), W_ - 1);
                const int cy0 = min(max(iy0, 0), H_ - 1);
                const int cy1 = min(max(iy1, 0), H_ - 1);
                const float w00 = (vx0 & vy0) ? wx0 * wy0 : 0.f;
                const float w10 = (vx1 & vy0) ? wx1 * wy0 : 0.f;
                const float w01 = (vx0 & vy1) ? wx0 * wy1 : 0.f;
                const float w11 = (vx1 & vy1) ? wx1 * wy1 : 0.f;
                val = w00 * fb[cy0 * W_ + cx0] + w10 * fb[cy0 * W_ + cx1]
                    + w01 * fb[cy1 * W_ + cx0] + w11 * fb[cy1 * W_ + cx1];
            }
            feat_s[pp][c] = val;
        }
    }
    __syncthreads();

    // ---------------- Phase 2: layer0 (128 <- 256), leaky relu ----------------
    {
        const int o  = tid & 127;
        const int pg = tid >> 7;          // 0..1
        const int p0 = pg * 8;
        const float* __restrict__ wr = W0 + (size_t)o * 256;
        float acc[8];
        #pragma unroll
        for (int i = 0; i < 8; ++i) acc[i] = 0.f;
        for (int k = 0; k < 256; k += 4) {
            const float4 w = *(const float4*)(wr + k);
            #pragma unroll
            for (int i = 0; i < 8; ++i) {
                const float4 f = *(const float4*)&feat_s[p0 + i][k];
                acc[i] += w.x * f.x + w.y * f.y + w.z * f.z + w.w * f.w;
            }
        }
        const float bias = b0[o];
        #pragma unroll
        for (int i = 0; i < 8; ++i) {
            const float v = acc[i] + bias;
            y0_s[p0 + i][o] = (v > 0.f) ? v : 0.01f * v;
        }
    }
    __syncthreads();

    // ---------------- Phase 3: layer1 (64 <- [128 y0 | 256 feat]), leaky relu ----------------
    {
        const int o  = tid & 63;
        const int pg = tid >> 6;          // 0..3
        const int p0 = pg * 4;
        const float* __restrict__ wr = W1 + (size_t)o * 384;
        float acc[4] = {0.f, 0.f, 0.f, 0.f};
        for (int k = 0; k < 128; k += 4) {
            const float4 w = *(const float4*)(wr + k);
            #pragma unroll
            for (int i = 0; i < 4; ++i) {
                const float4 f = *(const float4*)&y0_s[p0 + i][k];
                acc[i] += w.x * f.x + w.y * f.y + w.z * f.z + w.w * f.w;
            }
        }
        for (int k = 0; k < 256; k += 4) {
            const float4 w = *(const float4*)(wr + 128 + k);
            #pragma unroll
            for (int i = 0; i < 4; ++i) {
                const float4 f = *(const float4*)&feat_s[p0 + i][k];
                acc[i] += w.x * f.x + w.y * f.y + w.z * f.z + w.w * f.w;
            }
        }
        const float bias = b1[o];
        #pragma unroll
        for (int i = 0; i < 4; ++i) {
            const float v = acc[i] + bias;
            y1_s[p0 + i][o] = (v > 0.f) ? v : 0.01f * v;
        }
    }
    __syncthreads();

    // ---------------- Phase 4: layer2 (5 <- [64 y1 | 256 feat]), relu, store ----------------
    if (tid < 80) {
        const int o  = tid >> 4;          // 0..4
        const int pp = tid & 15;          // 0..15
        const float* __restrict__ wr = W2 + (size_t)o * 320;
        float acc = 0.f;
        for (int k = 0; k < 64; k += 4) {
            const float4 w = *(const float4*)(wr + k);
            const float4 f = *(const float4*)&y1_s[pp][k];
            acc += w.x * f.x + w.y * f.y + w.z * f.z + w.w * f.w;
        }
        for (int k = 0; k < 256; k += 4) {
            const float4 w = *(const float4*)(wr + 64 + k);
            const float4 f = *(const float4*)&feat_s[pp][k];
            acc += w.x * f.x + w.y * f.y + w.z * f.z + w.w * f.w;
        }
        const int n = n0 + pp;
        if (n < N_) {
            float v = acc + b2[o];
            v = (v > 0.f) ? v : 0.f;
            out[((size_t)b * 5 + o) * N_ + n] = v;
        }
    }
}

extern "C" void kernel_launch(void* const* d_in, const int* in_sizes, int n_in,
                              void* d_out, int out_size, void* d_ws, size_t ws_size,
                              hipStream_t stream) {
    const float* p     = (const float*)d_in[0];
    const float* cam   = (const float*)d_in[1];
    const float* sfeat = (const float*)d_in[2];
    const float* W0    = (const float*)d_in[3];
    const float* b0    = (const float*)d_in[4];
    const float* W1    = (const float*)d_in[5];
    const float* b1    = (const float*)d_in[6];
    const float* W2    = (const float*)d_in[7];
    const float* b2    = (const float*)d_in[8];
    // d_in[9] = res (unused by the math)
    float* out = (float*)d_out;

    dim3 grid(NT_, B_);
    maf_fused_kernel<<<grid, 256, 0, stream>>>(p, cam, sfeat, W0, b0, W1, b1, W2, b2, out);
}

// Round 2
// 475.645 us; speedup vs baseline: 1.0844x; 1.0844x over previous
//
#include <hip/hip_runtime.h>

// MAF_Extractor: projection -> bilinear grid_sample (B,C,H,W)@(B,N,2) -> 3-layer MLP
// B=64 N=431 C=256 H=W=56; dims 256->128, (128+256)->64, (64+256)->5
// R2: pre-transpose s_feat to (B,H,W,C) in d_ws so gather is coalesced (float4,
// contiguous 1KB per corner). Padded LDS (+4 floats) kills stride-256 bank hits.

#define B_   64
#define N_   431
#define C_   256
#define H_   56
#define W_   56
#define HW_  (H_ * W_)
#define PPB  16            // points per block
#define NT_  27            // ceil(431/16)

// ---------------- transpose (B,C,H,W) -> (B,H,W,C) ----------------
// tile: 64 channels x 64 pixels, 256 threads. HW_=3136=49*64 exact.
__global__ __launch_bounds__(256, 4) void transpose_kernel(
    const float* __restrict__ in, float* __restrict__ out)
{
    __shared__ float tile[64][67];     // 67: odd-ish stride, 2-way max on column reads
    const int pix0 = blockIdx.x * 64;  // 49
    const int c0   = blockIdx.y * 64;  // 4
    const int b    = blockIdx.z;       // 64
    const int t    = threadIdx.x;

    // read: float4 along pixels (coalesced 256B per 16-lane cluster)
    {
        const int cr = t >> 4;            // 0..15
        const int p4 = (t & 15) * 4;
        const float* inb = in + ((size_t)b * C_ + c0) * HW_ + pix0;
        #pragma unroll
        for (int i = 0; i < 4; ++i) {
            const int cc = cr + i * 16;
            const float4 v = *(const float4*)(inb + (size_t)cc * HW_ + p4);
            tile[cc][p4 + 0] = v.x;
            tile[cc][p4 + 1] = v.y;
            tile[cc][p4 + 2] = v.z;
            tile[cc][p4 + 3] = v.w;
        }
    }
    __syncthreads();
    // write: float4 along channels (coalesced)
    {
        const int c4 = (t & 15) * 4;
        const int pr = t >> 4;            // 0..15
        float* outb = out + ((size_t)b * HW_ + pix0) * C_ + c0;
        #pragma unroll
        for (int i = 0; i < 4; ++i) {
            const int pp = pr + i * 16;
            float4 v;
            v.x = tile[c4 + 0][pp];
            v.y = tile[c4 + 1][pp];
            v.z = tile[c4 + 2][pp];
            v.w = tile[c4 + 3][pp];
            *(float4*)(outb + (size_t)pp * C_ + c4) = v;
        }
    }
}

// ---------------- fused gather + MLP ----------------
// TR=true: sfeat is (B,HW,C) transposed. TR=false: original (B,C,HW) fallback.
template <bool TR>
__global__ __launch_bounds__(256, 4) void maf_fused_kernel(
    const float* __restrict__ p,     // (B,N,3)
    const float* __restrict__ cam,   // (B,3)
    const float* __restrict__ sfeat,
    const float* __restrict__ W0,    // (128,256)
    const float* __restrict__ b0,    // (128)
    const float* __restrict__ W1,    // (64,384)
    const float* __restrict__ b1,    // (64)
    const float* __restrict__ W2,    // (5,320)
    const float* __restrict__ b2,    // (5)
    float* __restrict__ out)         // (B,5,N)
{
    __shared__ float feat_s[PPB][C_ + 4];   // padded: column reads -> 2-way max
    __shared__ float y0_s[PPB][128 + 4];
    __shared__ float y1_s[PPB][64 + 4];

    const int tid  = threadIdx.x;
    const int tile = blockIdx.x;        // 0..26
    const int b    = blockIdx.y;        // 0..63
    const int n0   = tile * PPB;

    const float s  = cam[b * 3 + 0];
    const float tx = cam[b * 3 + 1];
    const float ty = cam[b * 3 + 2];

    // ---------------- Phase 1: bilinear gather ----------------
    if (TR) {
        // wave g handles points g, g+4, g+8, g+12; lane l covers channels 4l..4l+3
        const int g = tid >> 6;
        const int l = tid & 63;
        const float* __restrict__ tf = sfeat + (size_t)b * HW_ * C_;
        for (int pp = g; pp < PPB; pp += 4) {
            const int n = n0 + pp;
            float4 val = {0.f, 0.f, 0.f, 0.f};
            if (n < N_) {
                const float px = p[((size_t)b * N_ + n) * 3 + 0];
                const float py = p[((size_t)b * N_ + n) * 3 + 1];
                const float x = (s * (px + tx) + 1.f) * 0.5f * (float)(W_ - 1);
                const float y = (s * (py + ty) + 1.f) * 0.5f * (float)(H_ - 1);
                const float x0f = floorf(x), y0f = floorf(y);
                const float wx1 = x - x0f, wx0 = 1.f - wx1;
                const float wy1 = y - y0f, wy0 = 1.f - wy1;
                const int ix0 = (int)x0f, iy0 = (int)y0f;
                const int ix1 = ix0 + 1,  iy1 = iy0 + 1;
                const bool vx0 = (ix0 >= 0) & (ix0 <= W_ - 1);
                const bool vx1 = (ix1 >= 0) & (ix1 <= W_ - 1);
                const bool vy0 = (iy0 >= 0) & (iy0 <= H_ - 1);
                const bool vy1 = (iy1 >= 0) & (iy1 <= H_ - 1);
                const int cx0 = min(max(ix0, 0), W_ - 1);
                const int cx1 = min(max(ix1, 0), W_ - 1);
                const int cy0 = min(max(iy0, 0), H_ - 1);
                const int cy1 = min(max(iy1, 0), H_ - 1);
                const float w00 = (vx0 & vy0) ? wx0 * wy0 : 0.f;
                const float w10 = (vx1 & vy0) ? wx1 * wy0 : 0.f;
                const float w01 = (vx0 & vy1) ? wx0 * wy1 : 0.f;
                const float w11 = (vx1 & vy1) ? wx1 * wy1 : 0.f;
                const int c4 = l * 4;
                const float4 f00 = *(const float4*)(tf + (size_t)(cy0 * W_ + cx0) * C_ + c4);
                const float4 f10 = *(const float4*)(tf + (size_t)(cy0 * W_ + cx1) * C_ + c4);
                const float4 f01 = *(const float4*)(tf + (size_t)(cy1 * W_ + cx0) * C_ + c4);
                const float4 f11 = *(const float4*)(tf + (size_t)(cy1 * W_ + cx1) * C_ + c4);
                val.x = w00 * f00.x + w10 * f10.x + w01 * f01.x + w11 * f11.x;
                val.y = w00 * f00.y + w10 * f10.y + w01 * f01.y + w11 * f11.y;
                val.z = w00 * f00.z + w10 * f10.z + w01 * f01.z + w11 * f11.z;
                val.w = w00 * f00.w + w10 * f10.w + w01 * f01.w + w11 * f11.w;
            }
            *(float4*)&feat_s[pp][l * 4] = val;
        }
    } else {
        // fallback: original NCHW gather (uncoalesced)
        const int c = tid;
        const float* __restrict__ fb = sfeat + ((size_t)b * C_ + c) * HW_;
        #pragma unroll 4
        for (int pp = 0; pp < PPB; ++pp) {
            const int n = n0 + pp;
            float val = 0.f;
            if (n < N_) {
                const float px = p[((size_t)b * N_ + n) * 3 + 0];
                const float py = p[((size_t)b * N_ + n) * 3 + 1];
                const float x = (s * (px + tx) + 1.f) * 0.5f * (float)(W_ - 1);
                const float y = (s * (py + ty) + 1.f) * 0.5f * (float)(H_ - 1);
                const float x0f = floorf(x), y0f = floorf(y);
                const float wx1 = x - x0f, wx0 = 1.f - wx1;
                const float wy1 = y - y0f, wy0 = 1.f - wy1;
                const int ix0 = (int)x0f, iy0 = (int)y0f;
                const int ix1 = ix0 + 1,  iy1 = iy0 + 1;
                const bool vx0 = (ix0 >= 0) & (ix0 <= W_ - 1);
                const bool vx1 = (ix1 >= 0) & (ix1 <= W_ - 1);
                const bool vy0 = (iy0 >= 0) & (iy0 <= H_ - 1);
                const bool vy1 = (iy1 >= 0) & (iy1 <= H_ - 1);
                const int cx0 = min(max(ix0, 0), W_ - 1);
                const int cx1 = min(max(ix1, 0), W_ - 1);
                const int cy0 = min(max(iy0, 0), H_ - 1);
                const int cy1 = min(max(iy1, 0), H_ - 1);
                const float w00 = (vx0 & vy0) ? wx0 * wy0 : 0.f;
                const float w10 = (vx1 & vy0) ? wx1 * wy0 : 0.f;
                const float w01 = (vx0 & vy1) ? wx0 * wy1 : 0.f;
                const float w11 = (vx1 & vy1) ? wx1 * wy1 : 0.f;
                val = w00 * fb[cy0 * W_ + cx0] + w10 * fb[cy0 * W_ + cx1]
                    + w01 * fb[cy1 * W_ + cx0] + w11 * fb[cy1 * W_ + cx1];
            }
            feat_s[pp][c] = val;
        }
    }
    __syncthreads();

    // ---------------- Phase 2: layer0 (128 <- 256), leaky relu ----------------
    {
        const int o  = tid & 127;
        const int pg = tid >> 7;          // 0..1
        const int p0 = pg * 8;
        const float* __restrict__ wr = W0 + (size_t)o * 256;
        float acc[8];
        #pragma unroll
        for (int i = 0; i < 8; ++i) acc[i] = 0.f;
        for (int k = 0; k < 256; k += 4) {
            const float4 w = *(const float4*)(wr + k);
            #pragma unroll
            for (int i = 0; i < 8; ++i) {
                const float4 f = *(const float4*)&feat_s[p0 + i][k];
                acc[i] += w.x * f.x + w.y * f.y + w.z * f.z + w.w * f.w;
            }
        }
        const float bias = b0[o];
        #pragma unroll
        for (int i = 0; i < 8; ++i) {
            const float v = acc[i] + bias;
            y0_s[p0 + i][o] = (v > 0.f) ? v : 0.01f * v;
        }
    }
    __syncthreads();

    // ---------------- Phase 3: layer1 (64 <- [128 y0 | 256 feat]), leaky relu ----------------
    {
        const int o  = tid & 63;
        const int pg = tid >> 6;          // 0..3
        const int p0 = pg * 4;
        const float* __restrict__ wr = W1 + (size_t)o * 384;
        float acc[4] = {0.f, 0.f, 0.f, 0.f};
        for (int k = 0; k < 128; k += 4) {
            const float4 w = *(const float4*)(wr + k);
            #pragma unroll
            for (int i = 0; i < 4; ++i) {
                const float4 f = *(const float4*)&y0_s[p0 + i][k];
                acc[i] += w.x * f.x + w.y * f.y + w.z * f.z + w.w * f.w;
            }
        }
        for (int k = 0; k < 256; k += 4) {
            const float4 w = *(const float4*)(wr + 128 + k);
            #pragma unroll
            for (int i = 0; i < 4; ++i) {
                const float4 f = *(const float4*)&feat_s[p0 + i][k];
                acc[i] += w.x * f.x + w.y * f.y + w.z * f.z + w.w * f.w;
            }
        }
        const float bias = b1[o];
        #pragma unroll
        for (int i = 0; i < 4; ++i) {
            const float v = acc[i] + bias;
            y1_s[p0 + i][o] = (v > 0.f) ? v : 0.01f * v;
        }
    }
    __syncthreads();

    // ---------------- Phase 4: layer2 (5 <- [64 y1 | 256 feat]), relu, store ----------------
    if (tid < 80) {
        const int o  = tid >> 4;          // 0..4
        const int pp = tid & 15;          // 0..15
        const float* __restrict__ wr = W2 + (size_t)o * 320;
        float acc = 0.f;
        for (int k = 0; k < 64; k += 4) {
            const float4 w = *(const float4*)(wr + k);
            const float4 f = *(const float4*)&y1_s[pp][k];
            acc += w.x * f.x + w.y * f.y + w.z * f.z + w.w * f.w;
        }
        for (int k = 0; k < 256; k += 4) {
            const float4 w = *(const float4*)(wr + 64 + k);
            const float4 f = *(const float4*)&feat_s[pp][k];
            acc += w.x * f.x + w.y * f.y + w.z * f.z + w.w * f.w;
        }
        const int n = n0 + pp;
        if (n < N_) {
            float v = acc + b2[o];
            v = (v > 0.f) ? v : 0.f;
            out[((size_t)b * 5 + o) * N_ + n] = v;
        }
    }
}

extern "C" void kernel_launch(void* const* d_in, const int* in_sizes, int n_in,
                              void* d_out, int out_size, void* d_ws, size_t ws_size,
                              hipStream_t stream) {
    const float* p     = (const float*)d_in[0];
    const float* cam   = (const float*)d_in[1];
    const float* sfeat = (const float*)d_in[2];
    const float* W0    = (const float*)d_in[3];
    const float* b0    = (const float*)d_in[4];
    const float* W1    = (const float*)d_in[5];
    const float* b1    = (const float*)d_in[6];
    const float* W2    = (const float*)d_in[7];
    const float* b2    = (const float*)d_in[8];
    float* out = (float*)d_out;

    const size_t need = (size_t)B_ * C_ * HW_ * sizeof(float);  // 205 MB
    dim3 grid(NT_, B_);
    if (ws_size >= need) {
        float* tf = (float*)d_ws;
        transpose_kernel<<<dim3(HW_ / 64, C_ / 64, B_), 256, 0, stream>>>(sfeat, tf);
        maf_fused_kernel<true><<<grid, 256, 0, stream>>>(p, cam, tf, W0, b0, W1, b1, W2, b2, out);
    } else {
        maf_fused_kernel<false><<<grid, 256, 0, stream>>>(p, cam, sfeat, W0, b0, W1, b1, W2, b2, out);
    }
}

// Round 3
// 347.562 us; speedup vs baseline: 1.4840x; 1.3685x over previous
//
#include <hip/hip_runtime.h>

// MAF_Extractor R3: transpose s_feat (B,C,H,W) fp32 -> (B,H,W,C) bf16 in ws,
// pre-convert weights to bf16, then fused gather + 3-layer MLP via bf16 MFMA
// (16x16x32). B=64 N=431 C=256 H=W=56. Block = 16 points of one batch.

#define B_   64
#define N_   431
#define C_   256
#define H_   56
#define W_   56
#define HW_  (H_ * W_)
#define PPB  16
#define NT_  27            // ceil(431/16)

#define FS   264           // feat_s row stride (ushort): 256+8 -> 2-way banks
#define Y0S  136           // 128+8
#define Y1S  72            // 64+8

typedef __attribute__((ext_vector_type(8))) short short8;
typedef __attribute__((ext_vector_type(4))) float f32x4;

__device__ __forceinline__ ushort f2bf(float f) {
    unsigned u = __float_as_uint(f);
    u += 0x7fffu + ((u >> 16) & 1u);     // RNE
    return (ushort)(u >> 16);
}
__device__ __forceinline__ float bf2f(ushort h) {
    return __uint_as_float((unsigned)h << 16);
}

// ---------------- weights fp32 -> bf16 (W2 padded to 16 rows) ----------------
__global__ void convert_weights(const float* __restrict__ W0,
                                const float* __restrict__ W1,
                                const float* __restrict__ W2,
                                ushort* __restrict__ W0b,
                                ushort* __restrict__ W1b,
                                ushort* __restrict__ W2p)
{
    const int total = 128 * 256 + 64 * 384 + 16 * 320;
    for (int i = blockIdx.x * 256 + threadIdx.x; i < total; i += gridDim.x * 256) {
        if (i < 128 * 256) {
            W0b[i] = f2bf(W0[i]);
        } else if (i < 128 * 256 + 64 * 384) {
            const int j = i - 128 * 256;
            W1b[j] = f2bf(W1[j]);
        } else {
            const int j = i - (128 * 256 + 64 * 384);
            const int r = j / 320, c = j - r * 320;
            W2p[j] = (r < 5) ? f2bf(W2[r * 320 + c]) : (ushort)0;
        }
    }
}

// ---------------- transpose (B,C,H,W) fp32 -> (B,H,W,C) bf16 ----------------
__global__ __launch_bounds__(256, 4) void transpose_bf16(
    const float* __restrict__ in, ushort* __restrict__ out)
{
    __shared__ float tile[64][69];
    const int pix0 = blockIdx.x * 64;   // 49
    const int c0   = blockIdx.y * 64;   // 4
    const int b    = blockIdx.z;        // 64
    const int t    = threadIdx.x;

    {   // read: float4 along pixels
        const int cr = t >> 4;
        const int p4 = (t & 15) * 4;
        const float* inb = in + ((size_t)b * C_ + c0) * HW_ + pix0;
        #pragma unroll
        for (int i = 0; i < 4; ++i) {
            const int cc = cr + i * 16;
            const float4 v = *(const float4*)(inb + (size_t)cc * HW_ + p4);
            tile[cc][p4 + 0] = v.x;
            tile[cc][p4 + 1] = v.y;
            tile[cc][p4 + 2] = v.z;
            tile[cc][p4 + 3] = v.w;
        }
    }
    __syncthreads();
    {   // write: ushort4 along channels
        const int c4 = (t & 15) * 4;
        const int pr = t >> 4;
        ushort* outb = out + ((size_t)b * HW_ + pix0) * C_ + c0;
        #pragma unroll
        for (int i = 0; i < 4; ++i) {
            const int pp = pr + i * 16;
            ushort4 v;
            v.x = f2bf(tile[c4 + 0][pp]);
            v.y = f2bf(tile[c4 + 1][pp]);
            v.z = f2bf(tile[c4 + 2][pp]);
            v.w = f2bf(tile[c4 + 3][pp]);
            *(ushort4*)(outb + (size_t)pp * C_ + c4) = v;
        }
    }
}

// ---------------- fused gather + MFMA MLP ----------------
__global__ __launch_bounds__(256, 4) void maf_mfma_kernel(
    const float* __restrict__ p,      // (B,N,3)
    const float* __restrict__ cam,    // (B,3)
    const ushort* __restrict__ tf,    // (B,HW,C) bf16
    const ushort* __restrict__ W0b,   // (128,256) bf16
    const float* __restrict__ b0,
    const ushort* __restrict__ W1b,   // (64,384) bf16
    const float* __restrict__ b1,
    const ushort* __restrict__ W2p,   // (16,320) bf16, rows 5..15 = 0
    const float* __restrict__ b2,
    float* __restrict__ out)          // (B,5,N)
{
    __shared__ ushort feat_s[PPB * FS];
    __shared__ ushort y0_s[PPB * Y0S];
    __shared__ ushort y1_s[PPB * Y1S];

    const int tid = threadIdx.x;
    const int w   = tid >> 6;          // wave 0..3
    const int l   = tid & 63;
    const int m   = l & 15;            // MFMA row/col-lane index
    const int q   = l >> 4;            // quad
    const int b   = blockIdx.y;
    const int n0  = blockIdx.x * PPB;

    const float s  = cam[b * 3 + 0];
    const float tx = cam[b * 3 + 1];
    const float ty = cam[b * 3 + 2];

    // ---- Phase 1: bilinear gather -> feat_s (bf16), wave w owns points 4w..4w+3
    {
        const ushort* __restrict__ tb = tf + (size_t)b * HW_ * C_;
        const int c4 = l * 4;
        #pragma unroll
        for (int i = 0; i < 4; ++i) {
            const int pp = w * 4 + i;
            const int n  = n0 + pp;
            ushort4 r = {0, 0, 0, 0};
            if (n < N_) {
                const float px = p[((size_t)b * N_ + n) * 3 + 0];
                const float py = p[((size_t)b * N_ + n) * 3 + 1];
                const float x = (s * (px + tx) + 1.f) * 0.5f * (float)(W_ - 1);
                const float y = (s * (py + ty) + 1.f) * 0.5f * (float)(H_ - 1);
                const float x0f = floorf(x), y0f = floorf(y);
                const float wx1 = x - x0f, wx0 = 1.f - wx1;
                const float wy1 = y - y0f, wy0 = 1.f - wy1;
                const int ix0 = (int)x0f, iy0 = (int)y0f;
                const int ix1 = ix0 + 1,  iy1 = iy0 + 1;
                const bool vx0 = (ix0 >= 0) & (ix0 <= W_ - 1);
                const bool vx1 = (ix1 >= 0) & (ix1 <= W_ - 1);
                const bool vy0 = (iy0 >= 0) & (iy0 <= H_ - 1);
                const bool vy1 = (iy1 >= 0) & (iy1 <= H_ - 1);
                const int cx0 = min(max(ix0, 0), W_ - 1);
                const int cx1 = min(max(ix1, 0), W_ - 1);
                const int cy0 = min(max(iy0, 0), H_ - 1);
                const int cy1 = min(max(iy1, 0), H_ - 1);
                const float w00 = (vx0 & vy0) ? wx0 * wy0 : 0.f;
                const float w10 = (vx1 & vy0) ? wx1 * wy0 : 0.f;
                const float w01 = (vx0 & vy1) ? wx0 * wy1 : 0.f;
                const float w11 = (vx1 & vy1) ? wx1 * wy1 : 0.f;
                const ushort4 f00 = *(const ushort4*)(tb + (size_t)(cy0 * W_ + cx0) * C_ + c4);
                const ushort4 f10 = *(const ushort4*)(tb + (size_t)(cy0 * W_ + cx1) * C_ + c4);
                const ushort4 f01 = *(const ushort4*)(tb + (size_t)(cy1 * W_ + cx0) * C_ + c4);
                const ushort4 f11 = *(const ushort4*)(tb + (size_t)(cy1 * W_ + cx1) * C_ + c4);
                r.x = f2bf(w00 * bf2f(f00.x) + w10 * bf2f(f10.x) + w01 * bf2f(f01.x) + w11 * bf2f(f11.x));
                r.y = f2bf(w00 * bf2f(f00.y) + w10 * bf2f(f10.y) + w01 * bf2f(f01.y) + w11 * bf2f(f11.y));
                r.z = f2bf(w00 * bf2f(f00.z) + w10 * bf2f(f10.z) + w01 * bf2f(f01.z) + w11 * bf2f(f11.z));
                r.w = f2bf(w00 * bf2f(f00.w) + w10 * bf2f(f10.w) + w01 * bf2f(f01.w) + w11 * bf2f(f11.w));
            }
            *(ushort4*)&feat_s[pp * FS + c4] = r;
        }
    }
    __syncthreads();

    // ---- Phase 2: layer0 (128 <- 256), wave w -> output tiles 2w, 2w+1
    {
        f32x4 acc0 = {0.f, 0.f, 0.f, 0.f};
        f32x4 acc1 = {0.f, 0.f, 0.f, 0.f};
        const ushort* __restrict__ ar  = feat_s + m * FS + 8 * q;
        const ushort* __restrict__ wr0 = W0b + ((size_t)(2 * w) * 16 + m) * 256 + 8 * q;
        const ushort* __restrict__ wr1 = W0b + ((size_t)(2 * w + 1) * 16 + m) * 256 + 8 * q;
        #pragma unroll
        for (int ks = 0; ks < 8; ++ks) {
            const short8 a  = *(const short8*)(ar + 32 * ks);
            const short8 w0 = *(const short8*)(wr0 + 32 * ks);
            const short8 w1 = *(const short8*)(wr1 + 32 * ks);
            acc0 = __builtin_amdgcn_mfma_f32_16x16x32_bf16(a, w0, acc0, 0, 0, 0);
            acc1 = __builtin_amdgcn_mfma_f32_16x16x32_bf16(a, w1, acc1, 0, 0, 0);
        }
        const int o0 = (2 * w) * 16 + m, o1 = o0 + 16;
        const float bias0 = b0[o0], bias1 = b0[o1];
        #pragma unroll
        for (int r = 0; r < 4; ++r) {
            float v0 = acc0[r] + bias0; v0 = (v0 > 0.f) ? v0 : 0.01f * v0;
            float v1 = acc1[r] + bias1; v1 = (v1 > 0.f) ? v1 : 0.01f * v1;
            y0_s[(q * 4 + r) * Y0S + o0] = f2bf(v0);
            y0_s[(q * 4 + r) * Y0S + o1] = f2bf(v1);
        }
    }
    __syncthreads();

    // ---- Phase 3: layer1 (64 <- [128 y0 | 256 feat]), wave w -> output tile w
    {
        f32x4 acc = {0.f, 0.f, 0.f, 0.f};
        const ushort* __restrict__ wr = W1b + ((size_t)w * 16 + m) * 384 + 8 * q;
        #pragma unroll
        for (int ks = 0; ks < 12; ++ks) {
            short8 a;
            if (ks < 4) a = *(const short8*)(y0_s  + m * Y0S + 32 * ks + 8 * q);
            else        a = *(const short8*)(feat_s + m * FS + 32 * ks - 128 + 8 * q);
            const short8 bb = *(const short8*)(wr + 32 * ks);
            acc = __builtin_amdgcn_mfma_f32_16x16x32_bf16(a, bb, acc, 0, 0, 0);
        }
        const int o = w * 16 + m;
        const float bias = b1[o];
        #pragma unroll
        for (int r = 0; r < 4; ++r) {
            float v = acc[r] + bias; v = (v > 0.f) ? v : 0.01f * v;
            y1_s[(q * 4 + r) * Y1S + o] = f2bf(v);
        }
    }
    __syncthreads();

    // ---- Phase 4: layer2 (5 <- [64 y1 | 256 feat]) on wave 0, relu, store
    if (w == 0) {
        f32x4 acc = {0.f, 0.f, 0.f, 0.f};
        const ushort* __restrict__ wr = W2p + (size_t)m * 320 + 8 * q;
        #pragma unroll
        for (int ks = 0; ks < 10; ++ks) {
            short8 a;
            if (ks < 2) a = *(const short8*)(y1_s + m * Y1S + 32 * ks + 8 * q);
            else        a = *(const short8*)(feat_s + m * FS + 32 * ks - 64 + 8 * q);
            const short8 bb = *(const short8*)(wr + 32 * ks);
            acc = __builtin_amdgcn_mfma_f32_16x16x32_bf16(a, bb, acc, 0, 0, 0);
        }
        if (m < 5) {
            const float bias = b2[m];
            #pragma unroll
            for (int r = 0; r < 4; ++r) {
                const int n = n0 + q * 4 + r;
                if (n < N_) {
                    float v = acc[r] + bias;
                    out[((size_t)b * 5 + m) * N_ + n] = (v > 0.f) ? v : 0.f;
                }
            }
        }
    }
}

// ---------------- fp32 NCHW fallback (ws too small) ----------------
__global__ __launch_bounds__(256, 4) void maf_fallback_kernel(
    const float* __restrict__ p, const float* __restrict__ cam,
    const float* __restrict__ sfeat,
    const float* __restrict__ W0, const float* __restrict__ b0,
    const float* __restrict__ W1, const float* __restrict__ b1,
    const float* __restrict__ W2, const float* __restrict__ b2,
    float* __restrict__ out)
{
    __shared__ float feat_s[PPB][C_ + 4];
    __shared__ float y0_s[PPB][128 + 4];
    __shared__ float y1_s[PPB][64 + 4];

    const int tid = threadIdx.x;
    const int b   = blockIdx.y;
    const int n0  = blockIdx.x * PPB;
    const float s  = cam[b * 3 + 0];
    const float tx = cam[b * 3 + 1];
    const float ty = cam[b * 3 + 2];
    {
        const int c = tid;
        const float* __restrict__ fb = sfeat + ((size_t)b * C_ + c) * HW_;
        for (int pp = 0; pp < PPB; ++pp) {
            const int n = n0 + pp;
            float val = 0.f;
            if (n < N_) {
                const float px = p[((size_t)b * N_ + n) * 3 + 0];
                const float py = p[((size_t)b * N_ + n) * 3 + 1];
                const float x = (s * (px + tx) + 1.f) * 0.5f * (float)(W_ - 1);
                const float y = (s * (py + ty) + 1.f) * 0.5f * (float)(H_ - 1);
                const float x0f = floorf(x), y0f = floorf(y);
                const float wx1 = x - x0f, wx0 = 1.f - wx1;
                const float wy1 = y - y0f, wy0 = 1.f - wy1;
                const int ix0 = (int)x0f, iy0 = (int)y0f;
                const int ix1 = ix0 + 1,  iy1 = iy0 + 1;
                const bool vx0 = (ix0 >= 0) & (ix0 <= W_ - 1);
                const bool vx1 = (ix1 >= 0) & (ix1 <= W_ - 1);
                const bool vy0 = (iy0 >= 0) & (iy0 <= H_ - 1);
                const bool vy1 = (iy1 >= 0) & (iy1 <= H_ - 1);
                const int cx0 = min(max(ix0, 0), W_ - 1);
                const int cx1 = min(max(ix1, 0), W_ - 1);
                const int cy0 = min(max(iy0, 0), H_ - 1);
                const int cy1 = min(max(iy1, 0), H_ - 1);
                const float w00 = (vx0 & vy0) ? wx0 * wy0 : 0.f;
                const float w10 = (vx1 & vy0) ? wx1 * wy0 : 0.f;
                const float w01 = (vx0 & vy1) ? wx0 * wy1 : 0.f;
                const float w11 = (vx1 & vy1) ? wx1 * wy1 : 0.f;
                val = w00 * fb[cy0 * W_ + cx0] + w10 * fb[cy0 * W_ + cx1]
                    + w01 * fb[cy1 * W_ + cx0] + w11 * fb[cy1 * W_ + cx1];
            }
            feat_s[pp][c] = val;
        }
    }
    __syncthreads();
    {
        const int o = tid & 127, pg = tid >> 7, p0 = pg * 8;
        const float* __restrict__ wr = W0 + (size_t)o * 256;
        float acc[8] = {0, 0, 0, 0, 0, 0, 0, 0};
        for (int k = 0; k < 256; k += 4) {
            const float4 w = *(const float4*)(wr + k);
            for (int i = 0; i < 8; ++i) {
                const float4 f = *(const float4*)&feat_s[p0 + i][k];
                acc[i] += w.x * f.x + w.y * f.y + w.z * f.z + w.w * f.w;
            }
        }
        const float bias = b0[o];
        for (int i = 0; i < 8; ++i) {
            const float v = acc[i] + bias;
            y0_s[p0 + i][o] = (v > 0.f) ? v : 0.01f * v;
        }
    }
    __syncthreads();
    {
        const int o = tid & 63, pg = tid >> 6, p0 = pg * 4;
        const float* __restrict__ wr = W1 + (size_t)o * 384;
        float acc[4] = {0, 0, 0, 0};
        for (int k = 0; k < 128; k += 4) {
            const float4 w = *(const float4*)(wr + k);
            for (int i = 0; i < 4; ++i) {
                const float4 f = *(const float4*)&y0_s[p0 + i][k];
                acc[i] += w.x * f.x + w.y * f.y + w.z * f.z + w.w * f.w;
            }
        }
        for (int k = 0; k < 256; k += 4) {
            const float4 w = *(const float4*)(wr + 128 + k);
            for (int i = 0; i < 4; ++i) {
                const float4 f = *(const float4*)&feat_s[p0 + i][k];
                acc[i] += w.x * f.x + w.y * f.y + w.z * f.z + w.w * f.w;
            }
        }
        const float bias = b1[o];
        for (int i = 0; i < 4; ++i) {
            const float v = acc[i] + bias;
            y1_s[p0 + i][o] = (v > 0.f) ? v : 0.01f * v;
        }
    }
    __syncthreads();
    if (tid < 80) {
        const int o = tid >> 4, pp = tid & 15;
        const float* __restrict__ wr = W2 + (size_t)o * 320;
        float acc = 0.f;
        for (int k = 0; k < 64; k += 4) {
            const float4 w = *(const float4*)(wr + k);
            const float4 f = *(const float4*)&y1_s[pp][k];
            acc += w.x * f.x + w.y * f.y + w.z * f.z + w.w * f.w;
        }
        for (int k = 0; k < 256; k += 4) {
            const float4 w = *(const float4*)(wr + 64 + k);
            const float4 f = *(const float4*)&feat_s[pp][k];
            acc += w.x * f.x + w.y * f.y + w.z * f.z + w.w * f.w;
        }
        const int n = n0 + pp;
        if (n < N_) {
            float v = acc + b2[o];
            out[((size_t)b * 5 + o) * N_ + n] = (v > 0.f) ? v : 0.f;
        }
    }
}

extern "C" void kernel_launch(void* const* d_in, const int* in_sizes, int n_in,
                              void* d_out, int out_size, void* d_ws, size_t ws_size,
                              hipStream_t stream) {
    const float* p     = (const float*)d_in[0];
    const float* cam   = (const float*)d_in[1];
    const float* sfeat = (const float*)d_in[2];
    const float* W0    = (const float*)d_in[3];
    const float* b0    = (const float*)d_in[4];
    const float* W1    = (const float*)d_in[5];
    const float* b1    = (const float*)d_in[6];
    const float* W2    = (const float*)d_in[7];
    const float* b2    = (const float*)d_in[8];
    float* out = (float*)d_out;

    const size_t tf_elems = (size_t)B_ * HW_ * C_;       // bf16 map
    size_t off = tf_elems;
    const size_t w0_off = off; off += 128 * 256;
    const size_t w1_off = off; off += 64 * 384;
    const size_t w2_off = off; off += 16 * 320;
    const size_t need = off * sizeof(ushort);

    if (ws_size >= need) {
        ushort* tf  = (ushort*)d_ws;
        ushort* W0b = tf + w0_off;
        ushort* W1b = tf + w1_off;
        ushort* W2p = tf + w2_off;
        convert_weights<<<64, 256, 0, stream>>>(W0, W1, W2, W0b, W1b, W2p);
        transpose_bf16<<<dim3(HW_ / 64, C_ / 64, B_), 256, 0, stream>>>(sfeat, tf);
        maf_mfma_kernel<<<dim3(NT_, B_), 256, 0, stream>>>(
            p, cam, tf, W0b, b0, W1b, b1, W2p, b2, out);
    } else {
        maf_fallback_kernel<<<dim3(NT_, B_), 256, 0, stream>>>(
            p, cam, sfeat, W0, b0, W1, b1, W2, b2, out);
    }
}